// Round 14
// baseline (130.616 us; speedup 1.0000x reference)
//
#include <hip/hip_runtime.h>
#include <hip/hip_bf16.h>

#define NN 16384
#define DD 512
#define CC 256
#define CAP 192
#define NROW 32768
#define LOGSZ 8388608   // 32768*256 per mat

typedef short bf16x8 __attribute__((ext_vector_type(8)));
typedef short bf16x4 __attribute__((ext_vector_type(4)));
typedef short bf16x2 __attribute__((ext_vector_type(2)));
typedef float f32x4 __attribute__((ext_vector_type(4)));
typedef float f32x16 __attribute__((ext_vector_type(16)));

__device__ __forceinline__ short f2bf(float x) {
  __hip_bfloat16 h = __float2bfloat16(x);
  return __builtin_bit_cast(short, h);
}
__device__ __forceinline__ float bf2f(unsigned short u) {
  unsigned v = (unsigned)u << 16;
  return __builtin_bit_cast(float, v);
}

// 32768 rows -> per-(tensor,class) index lists. grid 128 x 256.
__global__ void k_bucket(const int* __restrict__ lab_s, const int* __restrict__ lab_t,
                         int* __restrict__ cur, int* __restrict__ idx) {
  const int i = blockIdx.x * 256 + threadIdx.x;
  const int t = i >> 14, r = i & 16383;
  const int c = (t ? lab_t : lab_s)[r];
  const int tc = t * 256 + c;
  const int pos = atomicAdd(&cur[tc], 1);
  if (pos < CAP) idx[tc * CAP + pos] = r;
}

// grid 512 (one block per (tensor,class)), 256 threads, f32x4 16B/lane.
__global__ void k_gather(const float* __restrict__ src, const float* __restrict__ trg,
                         const int* __restrict__ cur, const int* __restrict__ idx,
                         float* __restrict__ sum_s, float* __restrict__ sum_t,
                         float* __restrict__ cnt_s, float* __restrict__ cnt_t) {
  const int tc = blockIdx.x;
  const int t = tc >> 8, c = tc & 255;
  const float* feat = t ? trg : src;
  float* sum = t ? sum_t : sum_s;
  float* cnt = t ? cnt_t : cnt_s;
  const int tid = threadIdx.x;
  const int q = tid & 127, h = tid >> 7;
  const int count = min(cur[tc], CAP);

  __shared__ int lidx[CAP];
  __shared__ f32x4 sh[128];
  if (tid < count) lidx[tid] = idx[tc * CAP + tid];
  __syncthreads();

  f32x4 a = (f32x4){0.f, 0.f, 0.f, 0.f};
  f32x4 b = (f32x4){0.f, 0.f, 0.f, 0.f};
  int r = h;
  for (; r + 2 < count; r += 4) {
    a += *reinterpret_cast<const f32x4*>(feat + (size_t)lidx[r] * DD + q * 4);
    b += *reinterpret_cast<const f32x4*>(feat + (size_t)lidx[r + 2] * DD + q * 4);
  }
  if (r < count)
    a += *reinterpret_cast<const f32x4*>(feat + (size_t)lidx[r] * DD + q * 4);
  a += b;
  if (h == 1) sh[q] = a;
  __syncthreads();
  if (h == 0) {
    a += sh[q];
    *reinterpret_cast<f32x4*>(sum + c * DD + q * 4) = a;
    if (tid == 0) cnt[c] = (float)count;
  }
}

// grid = 256 (class/col), 256 threads.  32x32x16 B-fragment pack:
// e = kc*8192 + t32*1024 + ks*512 + (col31 + 32*hi)*8 + j
__global__ void k_u(const float* __restrict__ sum_s, const float* __restrict__ sum_t,
                    const float* __restrict__ cnt_s, const float* __restrict__ cnt_t,
                    unsigned short* __restrict__ Upk) {
  const int c = blockIdx.x, tid = threadIdx.x;
  const float cs = cnt_s[c], ct = cnt_t[c];
  const float rs = 1.f / cs, rt = 1.f / ct, rst = 1.f / (cs + ct);
  const int t32 = c >> 5, col31 = c & 31;
#pragma unroll
  for (int kk = 0; kk < 2; ++kk) {
    const int k = tid + kk * 256;
    const float ss = sum_s[c * DD + k], st = sum_t[c * DD + k];
    const int kc = k >> 5, ks = (k >> 4) & 1, hi = (k >> 3) & 1, j = k & 7;
    const int e = kc * 8192 + t32 * 1024 + ks * 512 + (col31 + 32 * hi) * 8 + j;
    Upk[0 * 131072 + e] = (unsigned short)f2bf(ss * rs);
    Upk[1 * 131072 + e] = (unsigned short)f2bf(st * rt);
    Upk[2 * 131072 + e] = (unsigned short)f2bf((ss + st) * rst);
  }
}

// ---------- PASS 1: col-split GEMM + logit store + atomic expsum ----------
// grid 1024 = 512 rowgroups x 2 class-halves. 512 thr (8 waves: wr=w>>2 rowtile
// of 32 rows, cw=w&3 -> 32-class tile per mat). Block: 64 rows x (128 cls x 3).
// acc = 3 x f32x16 = 48 regs -> 2 blocks/CU co-resident (cross-block slip).
__global__ __launch_bounds__(512, 4) void k_gemm(
    const float* __restrict__ src, const float* __restrict__ trg,
    const unsigned short* __restrict__ Upk,
    float* __restrict__ lseSum, unsigned short* __restrict__ Lg) {
  __shared__ short Bs[2][12288];   // 2 x 24 KB: 24 units of 1KB per chunk
  __shared__ short As[2][2048];    // 2 x 4 KB: (rowtile,ks) x 512 shorts
  __shared__ float part[4][3][64];

  const int tid = threadIdx.x;
  const int w = tid >> 6, lane = tid & 63;
  const int hi = lane >> 5, l31 = lane & 31;
  const int wr = w >> 2, cw = w & 3;
  const int bid = blockIdx.x;
  const int rg = bid >> 1, ch = bid & 1;
  const int row0 = rg * 64;
  const float* feat = (row0 < NN) ? src + (size_t)row0 * DD
                                  : trg + (size_t)(row0 - NN) * DD;

  // A staging: thread -> (row ar 0..63, float4 slot aq 0..7)
  const int ar = tid >> 3, aq = tid & 7;
  const float* aglob = feat + (size_t)ar * DD + aq * 4;
  const int awoff = ((ar >> 5) * 2 + (aq >> 2)) * 512 +
                    ((ar & 31) + 32 * ((aq >> 1) & 1)) * 8 + (aq & 1) * 4;

  f32x16 acc[3];
#pragma unroll
  for (int m = 0; m < 3; ++m)
#pragma unroll
    for (int r = 0; r < 16; ++r) acc[m][r] = 0.f;

  auto stageB = [&](int kc, int buf) {
#pragma unroll
    for (int s = 0; s < 3; ++s) {
      const int lu = s * 8 + w;             // 24 local units
      const int m = lu >> 3, r8 = lu & 7, tw = r8 >> 1, ks = r8 & 1;
      const unsigned short* g = Upk + (size_t)m * 131072 + kc * 8192 +
                                (ch * 4 + tw) * 1024 + ks * 512 + lane * 8;
      __builtin_amdgcn_global_load_lds(
          (const __attribute__((address_space(1))) unsigned int*)g,
          (__attribute__((address_space(3))) unsigned int*)&Bs[buf][lu * 512], 16, 0, 0);
    }
  };
  auto writeA = [&](const float4& v, int buf) {
    bf16x4 b;
    b[0] = f2bf(v.x); b[1] = f2bf(v.y); b[2] = f2bf(v.z); b[3] = f2bf(v.w);
    *reinterpret_cast<bf16x4*>(&As[buf][awoff]) = b;
  };
  auto compute = [&](int buf) {
    const bf16x8 a0 =
        *reinterpret_cast<const bf16x8*>(&As[buf][(wr * 2 + 0) * 512 + lane * 8]);
    const bf16x8 a1 =
        *reinterpret_cast<const bf16x8*>(&As[buf][(wr * 2 + 1) * 512 + lane * 8]);
#pragma unroll
    for (int m = 0; m < 3; ++m) {
      const bf16x8 b0 = *reinterpret_cast<const bf16x8*>(
          &Bs[buf][(m * 8 + cw * 2 + 0) * 512 + lane * 8]);
      const bf16x8 b1 = *reinterpret_cast<const bf16x8*>(
          &Bs[buf][(m * 8 + cw * 2 + 1) * 512 + lane * 8]);
      acc[m] = __builtin_amdgcn_mfma_f32_32x32x16_bf16(a0, b0, acc[m], 0, 0, 0);
      acc[m] = __builtin_amdgcn_mfma_f32_32x32x16_bf16(a1, b1, acc[m], 0, 0, 0);
    }
  };

  // prologue (R12-proven single-barrier pipeline)
  float4 af = *reinterpret_cast<const float4*>(aglob);
  asm volatile("" ::: "memory");
  stageB(0, 0);
  writeA(af, 0);

#pragma unroll 1
  for (int kc = 0; kc < 16; ++kc) {
    asm volatile("s_waitcnt vmcnt(0) lgkmcnt(0)" ::: "memory");
    if (kc < 15)
      af = *reinterpret_cast<const float4*>(aglob + (kc + 1) * 32);
    __builtin_amdgcn_s_barrier();
    if (kc < 15) stageB(kc + 1, (kc + 1) & 1);
    compute(kc & 1);
    if (kc < 15) writeA(af, (kc + 1) & 1);
  }

  // epilogue: store bf16 logits + per-row partial expsum
  // C/D layout: col = l31, row = (r&3) + 8*(r>>2) + 4*hi
#pragma unroll
  for (int m = 0; m < 3; ++m) {
#pragma unroll
    for (int r = 0; r < 16; ++r) {
      const int rl = wr * 32 + (r & 3) + 8 * (r >> 2) + 4 * hi;
      const float v = acc[m][r];
      Lg[(size_t)m * LOGSZ + (size_t)(row0 + rl) * CC + ch * 128 + cw * 32 + l31] =
          (unsigned short)f2bf(v);
      float e = __expf(v);
      e += __shfl_xor(e, 1); e += __shfl_xor(e, 2);
      e += __shfl_xor(e, 4); e += __shfl_xor(e, 8); e += __shfl_xor(e, 16);
      if (l31 == 0) part[cw][m][rl] = e;
    }
  }
  __syncthreads();
  if (tid < 192) {
    const int m = tid >> 6, rl = tid & 63;
    const float S = part[0][m][rl] + part[1][m][rl] + part[2][m][rl] + part[3][m][rl];
    atomicAdd(&lseSum[m * NROW + row0 + rl], S);
  }
}

// ---------- PASS 2: streaming fused symmetric-KL ----------
// grid 2048 x 256: thread -> (row, 16-class block). Reads 3x32B bf16 + lse.
__global__ void k_kl(const unsigned short* __restrict__ Lg,
                     const float* __restrict__ lseSum, float* __restrict__ out) {
  const int gi = blockIdx.x * 256 + threadIdx.x;   // 0..524287
  const int row = gi >> 4, cb = gi & 15;
  const float la = __logf(lseSum[row]);
  const float lb = __logf(lseSum[NROW + row]);
  const float lc = __logf(lseSum[2 * NROW + row]);
  const size_t base = (size_t)row * CC + cb * 16;

  float ks = 0.f;
#pragma unroll
  for (int hh = 0; hh < 2; ++hh) {
    const bf16x8 pa = *reinterpret_cast<const bf16x8*>(Lg + 0 * LOGSZ + base + hh * 8);
    const bf16x8 pb = *reinterpret_cast<const bf16x8*>(Lg + 1 * LOGSZ + base + hh * 8);
    const bf16x8 pc = *reinterpret_cast<const bf16x8*>(Lg + 2 * LOGSZ + base + hh * 8);
#pragma unroll
    for (int j = 0; j < 8; ++j) {
      const float a = bf2f((unsigned short)pa[j]) - la;
      const float b = bf2f((unsigned short)pb[j]) - lb;
      const float c = bf2f((unsigned short)pc[j]) - lc;
      ks += __expf(a) * (2.f * a - b - c) + __expf(b) * (2.f * b - a - c) +
            __expf(c) * (2.f * c - a - b);
    }
  }
#pragma unroll
  for (int off = 1; off < 64; off <<= 1)
    ks += __shfl_xor(ks, off);
  __shared__ float bred[4];
  const int wv = threadIdx.x >> 6;
  if ((threadIdx.x & 63) == 0) bred[wv] = ks;
  __syncthreads();
  if (threadIdx.x == 0)
    atomicAdd(out, (bred[0] + bred[1] + bred[2] + bred[3]) * (1.f / 50331648.f));
}

// ---------- FALLBACK (R13 fused k_main, used if ws too small) ----------
__global__ __launch_bounds__(1024, 4) void k_main(
    const float* __restrict__ src, const float* __restrict__ trg,
    const unsigned short* __restrict__ Upk, float* __restrict__ out) {
  __shared__ short Bs[3][24576];
  __shared__ short As[2][2048];
  __shared__ float sLse[3][64];
  __shared__ float bred[16];

  const int tid = threadIdx.x;
  const int w = tid >> 6, lane = tid & 63;
  const int hi = lane >> 5, l31 = lane & 31;
  const int wr = w >> 3, cw = w & 7;
  const int row0 = blockIdx.x * 64;
  const float* feat = (row0 < NN) ? src + (size_t)row0 * DD
                                  : trg + (size_t)(row0 - NN) * DD;
  const int ar = tid >> 4, aq = tid & 15;
  const float* aglob = feat + (size_t)ar * DD + aq * 2;
  const int awoff = (ar >> 5) * 1024 + (aq >> 3) * 512 +
                    ((ar & 31) + 32 * ((aq >> 2) & 1)) * 8 + ((aq * 2) & 7);

  f32x16 acc[3];
#pragma unroll
  for (int m = 0; m < 3; ++m)
#pragma unroll
    for (int r = 0; r < 16; ++r) acc[m][r] = 0.f;

  auto stageB = [&](int kc, int buf) {
#pragma unroll
    for (int s = 0; s < 3; ++s) {
      const int u = s * 16 + w;
      const unsigned short* g =
          Upk + (size_t)(u >> 4) * 131072 + kc * 8192 + (u & 15) * 512 + lane * 8;
      __builtin_amdgcn_global_load_lds(
          (const __attribute__((address_space(1))) unsigned int*)g,
          (__attribute__((address_space(3))) unsigned int*)&Bs[buf][u * 512], 16, 0, 0);
    }
  };
  auto writeA = [&](const float2& v, int buf) {
    bf16x2 b;
    b[0] = f2bf(v.x); b[1] = f2bf(v.y);
    *reinterpret_cast<bf16x2*>(&As[buf][awoff]) = b;
  };
  auto compute = [&](int buf) {
    const bf16x8 a0 =
        *reinterpret_cast<const bf16x8*>(&As[buf & 1][(wr * 2 + 0) * 512 + lane * 8]);
    const bf16x8 a1 =
        *reinterpret_cast<const bf16x8*>(&As[buf & 1][(wr * 2 + 1) * 512 + lane * 8]);
    const int bb3 = buf % 3;
#pragma unroll
    for (int m = 0; m < 3; ++m) {
      const bf16x8 b0 = *reinterpret_cast<const bf16x8*>(
          &Bs[bb3][(m * 16 + cw * 2 + 0) * 512 + lane * 8]);
      const bf16x8 b1 = *reinterpret_cast<const bf16x8*>(
          &Bs[bb3][(m * 16 + cw * 2 + 1) * 512 + lane * 8]);
      acc[m] = __builtin_amdgcn_mfma_f32_32x32x16_bf16(a0, b0, acc[m], 0, 0, 0);
      acc[m] = __builtin_amdgcn_mfma_f32_32x32x16_bf16(a1, b1, acc[m], 0, 0, 0);
    }
  };

  float2 af = *reinterpret_cast<const float2*>(aglob);
  asm volatile("" ::: "memory");
  stageB(0, 0);
  writeA(af, 0);
  af = *reinterpret_cast<const float2*>(aglob + 32);
  asm volatile("" ::: "memory");
  stageB(1, 1);

#pragma unroll 1
  for (int kc = 0; kc < 16; ++kc) {
    if (kc < 14)
      asm volatile("s_waitcnt vmcnt(4) lgkmcnt(0)" ::: "memory");
    else
      asm volatile("s_waitcnt vmcnt(0) lgkmcnt(0)" ::: "memory");
    __builtin_amdgcn_s_barrier();
    if (kc + 2 < 16) stageB(kc + 2, (kc + 2) % 3);
    if (kc + 1 < 16) {
      writeA(af, (kc + 1) & 1);
      if (kc + 2 < 16) {
        af = *reinterpret_cast<const float2*>(aglob + (kc + 2) * 32);
        asm volatile("" ::: "memory");
      }
    }
    compute(kc);
  }

  __syncthreads();
  float* T = (float*)&Bs[0][0];
  const int erow = tid >> 4, ecc = tid & 15;
#pragma unroll
  for (int m = 0; m < 3; ++m) {
#pragma unroll
    for (int r = 0; r < 16; ++r) {
      const int row = wr * 32 + (r & 3) + 8 * (r >> 2) + 4 * hi;
      T[row * 260 + cw * 32 + l31] = acc[m][r];
    }
    __syncthreads();
    float s = 0.f;
    const float* tb = &T[erow * 260 + ecc * 16];
#pragma unroll
    for (int j = 0; j < 4; ++j) {
      const f32x4 v = *reinterpret_cast<const f32x4*>(tb + j * 4);
      s += __expf(v[0]) + __expf(v[1]) + __expf(v[2]) + __expf(v[3]);
    }
    s += __shfl_xor(s, 1); s += __shfl_xor(s, 2);
    s += __shfl_xor(s, 4); s += __shfl_xor(s, 8);
    if (ecc == 0) sLse[m][erow] = __logf(s);
    __syncthreads();
  }
  float ks = 0.f;
#pragma unroll
  for (int r = 0; r < 16; ++r) {
    const int row = wr * 32 + (r & 3) + 8 * (r >> 2) + 4 * hi;
    const float a = acc[0][r] - sLse[0][row];
    const float b = acc[1][r] - sLse[1][row];
    const float c = acc[2][r] - sLse[2][row];
    ks += __expf(a) * (2.f * a - b - c) + __expf(b) * (2.f * b - a - c) +
          __expf(c) * (2.f * c - a - b);
  }
#pragma unroll
  for (int off = 1; off < 64; off <<= 1)
    ks += __shfl_xor(ks, off);
  if (lane == 0) bred[w] = ks;
  __syncthreads();
  if (tid == 0) {
    float s = 0.f;
#pragma unroll
    for (int i = 0; i < 16; ++i) s += bred[i];
    atomicAdd(out, s * (1.f / 50331648.f));
  }
}

extern "C" void kernel_launch(void* const* d_in, const int* in_sizes, int n_in,
                              void* d_out, int out_size, void* d_ws, size_t ws_size,
                              hipStream_t stream) {
  const float* src = (const float*)d_in[0];
  const float* trg = (const float*)d_in[1];
  const int* lab_s = (const int*)d_in[2];
  const int* lab_t = (const int*)d_in[3];
  float* out = (float*)d_out;

  char* p = (char*)d_ws;
  float* sum_s = (float*)p;                         p += 524288;
  float* sum_t = (float*)p;                         p += 524288;
  float* cnt_s = (float*)p;                         p += 1024;
  float* cnt_t = (float*)p;                         p += 1024;
  int* cur = (int*)p;                               p += 2048;
  int* idx = (int*)p;                               p += 512 * CAP * 4;
  unsigned short* Upk = (unsigned short*)p;         p += 786432;
  float* lseSum = (float*)p;                        p += 3 * NROW * 4;
  unsigned short* Lg = (unsigned short*)p;          p += (size_t)3 * LOGSZ * 2;
  const size_t need = (size_t)(p - (char*)d_ws);

  hipMemsetAsync(cur, 0, 2048, stream);
  hipMemsetAsync(out, 0, (size_t)out_size * sizeof(float), stream);
  k_bucket<<<128, 256, 0, stream>>>(lab_s, lab_t, cur, idx);
  k_gather<<<512, 256, 0, stream>>>(src, trg, cur, idx, sum_s, sum_t, cnt_s, cnt_t);
  k_u<<<CC, 256, 0, stream>>>(sum_s, sum_t, cnt_s, cnt_t, Upk);

  if (ws_size >= need) {
    hipMemsetAsync(lseSum, 0, 3 * NROW * 4, stream);
    k_gemm<<<1024, 512, 0, stream>>>(src, trg, Upk, lseSum, Lg);
    k_kl<<<2048, 256, 0, stream>>>(Lg, lseSum, out);
  } else {
    k_main<<<512, 1024, 0, stream>>>(src, trg, Upk, out);
  }
}

// Round 15
// 82.828 us; speedup vs baseline: 1.5769x; 1.5769x over previous
//
#include <hip/hip_runtime.h>
#include <hip/hip_bf16.h>

#define NN 16384
#define DD 512
#define CC 256
#define CAP 192

typedef short bf16x8 __attribute__((ext_vector_type(8)));
typedef short bf16x2 __attribute__((ext_vector_type(2)));
typedef float f32x4 __attribute__((ext_vector_type(4)));
typedef float f32x16 __attribute__((ext_vector_type(16)));

__device__ __forceinline__ short f2bf(float x) {
  __hip_bfloat16 h = __float2bfloat16(x);
  return __builtin_bit_cast(short, h);
}

// 32768 rows -> per-(tensor,class) index lists. grid 128 x 256.
__global__ void k_bucket(const int* __restrict__ lab_s, const int* __restrict__ lab_t,
                         int* __restrict__ cur, int* __restrict__ idx) {
  const int i = blockIdx.x * 256 + threadIdx.x;
  const int t = i >> 14, r = i & 16383;
  const int c = (t ? lab_t : lab_s)[r];
  const int tc = t * 256 + c;
  const int pos = atomicAdd(&cur[tc], 1);
  if (pos < CAP) idx[tc * CAP + pos] = r;
}

// grid 512 (one block per (tensor,class)), 256 threads, f32x4 16B/lane.
__global__ void k_gather(const float* __restrict__ src, const float* __restrict__ trg,
                         const int* __restrict__ cur, const int* __restrict__ idx,
                         float* __restrict__ sum_s, float* __restrict__ sum_t,
                         float* __restrict__ cnt_s, float* __restrict__ cnt_t) {
  const int tc = blockIdx.x;
  const int t = tc >> 8, c = tc & 255;
  const float* feat = t ? trg : src;
  float* sum = t ? sum_t : sum_s;
  float* cnt = t ? cnt_t : cnt_s;
  const int tid = threadIdx.x;
  const int q = tid & 127, h = tid >> 7;
  const int count = min(cur[tc], CAP);

  __shared__ int lidx[CAP];
  __shared__ f32x4 sh[128];
  if (tid < count) lidx[tid] = idx[tc * CAP + tid];
  __syncthreads();

  f32x4 a = (f32x4){0.f, 0.f, 0.f, 0.f};
  f32x4 b = (f32x4){0.f, 0.f, 0.f, 0.f};
  int r = h;
  for (; r + 2 < count; r += 4) {
    a += *reinterpret_cast<const f32x4*>(feat + (size_t)lidx[r] * DD + q * 4);
    b += *reinterpret_cast<const f32x4*>(feat + (size_t)lidx[r + 2] * DD + q * 4);
  }
  if (r < count)
    a += *reinterpret_cast<const f32x4*>(feat + (size_t)lidx[r] * DD + q * 4);
  a += b;
  if (h == 1) sh[q] = a;
  __syncthreads();
  if (h == 0) {
    a += sh[q];
    *reinterpret_cast<f32x4*>(sum + c * DD + q * 4) = a;
    if (tid == 0) cnt[c] = (float)count;
  }
}

// grid = 256 (class/col), 256 threads.  Packs u_s, u_t in 32x32x16 B-fragment
// order (2 mats only; u_st is a per-column linear combo reconstructed later):
// e = kc*8192 + t32*1024 + ks*512 + (col31 + 32*hi)*8 + j.  Also w[c]=cs/(cs+ct).
__global__ void k_u(const float* __restrict__ sum_s, const float* __restrict__ sum_t,
                    const float* __restrict__ cnt_s, const float* __restrict__ cnt_t,
                    unsigned short* __restrict__ Upk, float* __restrict__ wcol) {
  const int c = blockIdx.x, tid = threadIdx.x;
  const float cs = cnt_s[c], ct = cnt_t[c];
  const float rs = 1.f / cs, rt = 1.f / ct;
  const int t32 = c >> 5, col31 = c & 31;
#pragma unroll
  for (int kk = 0; kk < 2; ++kk) {
    const int k = tid + kk * 256;
    const float ss = sum_s[c * DD + k], st = sum_t[c * DD + k];
    const int kc = k >> 5, ks = (k >> 4) & 1, hi = (k >> 3) & 1, j = k & 7;
    const int e = kc * 8192 + t32 * 1024 + ks * 512 + (col31 + 32 * hi) * 8 + j;
    Upk[0 * 131072 + e] = (unsigned short)f2bf(ss * rs);
    Upk[1 * 131072 + e] = (unsigned short)f2bf(st * rt);
  }
  if (tid == 0) wcol[c] = cs / (cs + ct);
}

// grid = 512 blocks, 1024 threads (16 waves: wr=w>>3 rowtile of 32 rows,
// cw=w&7 coltile of 32 cols per mat). Block: 64 rows x (256 cols x 2 mats).
// TWO GEMMs only; L_st = w*L_s + (1-w)*L_t in epilogue (exact identity).
// R12 single-barrier dbuf pipeline. LDS: B 2x32KB + A 2x4KB = 72KB.
__global__ __launch_bounds__(1024, 4) void k_main(
    const float* __restrict__ src, const float* __restrict__ trg,
    const unsigned short* __restrict__ Upk, const float* __restrict__ wcol,
    float* __restrict__ out) {
  __shared__ short SMEM[36864];    // 72KB: Bs = [0,32768), As = [32768,36864)
  __shared__ float sLse[3][64];
  __shared__ float bred[16];
  short* const Bs0 = &SMEM[0];
  short* const As0 = &SMEM[32768];

  const int tid = threadIdx.x;
  const int w = tid >> 6, lane = tid & 63;
  const int hi = lane >> 5, l31 = lane & 31;
  const int wr = w >> 3, cw = w & 7;
  const int row0 = blockIdx.x * 64;
  const float* feat = (row0 < NN) ? src + (size_t)row0 * DD
                                  : trg + (size_t)(row0 - NN) * DD;

  // A staging: thread -> (row ar 0..63, float2 slot aq 0..15)
  const int ar = tid >> 4, aq = tid & 15;
  const float* aglob = feat + (size_t)ar * DD + aq * 2;
  const int awoff = (ar >> 5) * 1024 + (aq >> 3) * 512 +
                    ((ar & 31) + 32 * ((aq >> 2) & 1)) * 8 + ((aq * 2) & 7);

  f32x16 acc[2];
#pragma unroll
  for (int m = 0; m < 2; ++m)
#pragma unroll
    for (int r = 0; r < 16; ++r) acc[m][r] = 0.f;

  auto stageB = [&](int kc, int buf) {
#pragma unroll
    for (int s = 0; s < 2; ++s) {
      const int u = s * 16 + w;   // 32 units: mat = u>>4, tile = u&15
      const unsigned short* g =
          Upk + (size_t)(u >> 4) * 131072 + kc * 8192 + (u & 15) * 512 + lane * 8;
      __builtin_amdgcn_global_load_lds(
          (const __attribute__((address_space(1))) unsigned int*)g,
          (__attribute__((address_space(3))) unsigned int*)&Bs0[buf * 16384 + u * 512],
          16, 0, 0);
    }
  };
  auto writeA = [&](const float2& v, int buf) {
    bf16x2 b;
    b[0] = f2bf(v.x); b[1] = f2bf(v.y);
    *reinterpret_cast<bf16x2*>(&As0[buf * 2048 + awoff]) = b;
  };
  auto compute = [&](int buf) {
    const bf16x8 a0 = *reinterpret_cast<const bf16x8*>(
        &As0[buf * 2048 + (wr * 2 + 0) * 512 + lane * 8]);
    const bf16x8 a1 = *reinterpret_cast<const bf16x8*>(
        &As0[buf * 2048 + (wr * 2 + 1) * 512 + lane * 8]);
#pragma unroll
    for (int m = 0; m < 2; ++m) {
      const bf16x8 b0 = *reinterpret_cast<const bf16x8*>(
          &Bs0[buf * 16384 + (m * 16 + cw * 2 + 0) * 512 + lane * 8]);
      const bf16x8 b1 = *reinterpret_cast<const bf16x8*>(
          &Bs0[buf * 16384 + (m * 16 + cw * 2 + 1) * 512 + lane * 8]);
      acc[m] = __builtin_amdgcn_mfma_f32_32x32x16_bf16(a0, b0, acc[m], 0, 0, 0);
      acc[m] = __builtin_amdgcn_mfma_f32_32x32x16_bf16(a1, b1, acc[m], 0, 0, 0);
    }
  };

  // ---- prologue ----
  float2 af = *reinterpret_cast<const float2*>(aglob);   // A(0)
  asm volatile("" ::: "memory");
  stageB(0, 0);
  writeA(af, 0);

#pragma unroll 1
  for (int kc = 0; kc < 16; ++kc) {
    asm volatile("s_waitcnt vmcnt(0) lgkmcnt(0)" ::: "memory");
    if (kc < 15)
      af = *reinterpret_cast<const float2*>(aglob + (kc + 1) * 32);
    __builtin_amdgcn_s_barrier();
    if (kc < 15) stageB(kc + 1, (kc + 1) & 1);
    compute(kc & 1);
    if (kc < 15) writeA(af, (kc + 1) & 1);
  }

  // ---- epilogue ----
  // C/D layout: col = l31 (of tile cw), row = (r&3) + 8*(r>>2) + 4*hi.
  // Reconstruct L_st = w*L_s + (1-w)*L_t (exact); then 3x LSE via transpose.
  const float wv = wcol[cw * 32 + l31];
  f32x16 cacc;
#pragma unroll
  for (int r = 0; r < 16; ++r)
    cacc[r] = wv * acc[0][r] + (1.f - wv) * acc[1][r];

  __syncthreads();
  float* T = (float*)&SMEM[0];     // 64 x 260 floats = 66.6 KB < 72 KB
  const int erow = tid >> 4, ecc = tid & 15;

  auto lsePass = [&](const f32x16& v, int m) {
#pragma unroll
    for (int r = 0; r < 16; ++r) {
      const int row = wr * 32 + (r & 3) + 8 * (r >> 2) + 4 * hi;
      T[row * 260 + cw * 32 + l31] = v[r];
    }
    __syncthreads();
    float s = 0.f;
    const float* tb = &T[erow * 260 + ecc * 16];
#pragma unroll
    for (int j = 0; j < 4; ++j) {
      const f32x4 x = *reinterpret_cast<const f32x4*>(tb + j * 4);
      s += __expf(x[0]) + __expf(x[1]) + __expf(x[2]) + __expf(x[3]);
    }
    s += __shfl_xor(s, 1); s += __shfl_xor(s, 2);
    s += __shfl_xor(s, 4); s += __shfl_xor(s, 8);
    if (ecc == 0) sLse[m][erow] = __logf(s);
    __syncthreads();
  };
  lsePass(acc[0], 0);
  lsePass(acc[1], 1);
  lsePass(cacc, 2);

  // fused symmetric-KL: sum of e^a(2a-b-c) + e^b(2b-a-c) + e^c(2c-a-b)
  float ks = 0.f;
#pragma unroll
  for (int r = 0; r < 16; ++r) {
    const int row = wr * 32 + (r & 3) + 8 * (r >> 2) + 4 * hi;
    const float a = acc[0][r] - sLse[0][row];
    const float b = acc[1][r] - sLse[1][row];
    const float c = cacc[r] - sLse[2][row];
    ks += __expf(a) * (2.f * a - b - c) + __expf(b) * (2.f * b - a - c) +
          __expf(c) * (2.f * c - a - b);
  }
#pragma unroll
  for (int off = 1; off < 64; off <<= 1)
    ks += __shfl_xor(ks, off);
  if (lane == 0) bred[w] = ks;
  __syncthreads();
  if (tid == 0) {
    float s = 0.f;
#pragma unroll
    for (int i = 0; i < 16; ++i) s += bred[i];
    atomicAdd(out, s * (1.f / 50331648.f));  // 1/(6 * 2N * C)
  }
}

extern "C" void kernel_launch(void* const* d_in, const int* in_sizes, int n_in,
                              void* d_out, int out_size, void* d_ws, size_t ws_size,
                              hipStream_t stream) {
  const float* src = (const float*)d_in[0];
  const float* trg = (const float*)d_in[1];
  const int* lab_s = (const int*)d_in[2];
  const int* lab_t = (const int*)d_in[3];
  float* out = (float*)d_out;

  char* p = (char*)d_ws;
  float* sum_s = (float*)p;                  p += 524288;
  float* sum_t = (float*)p;                  p += 524288;
  float* cnt_s = (float*)p;                  p += 1024;
  float* cnt_t = (float*)p;                  p += 1024;
  int* cur = (int*)p;                        p += 2048;
  int* idx = (int*)p;                        p += 512 * CAP * 4;
  unsigned short* Upk = (unsigned short*)p;  p += 2 * 131072 * 2;
  float* wcol = (float*)p;                   p += 1024;

  hipMemsetAsync(cur, 0, 2048, stream);
  hipMemsetAsync(out, 0, (size_t)out_size * sizeof(float), stream);
  k_bucket<<<128, 256, 0, stream>>>(lab_s, lab_t, cur, idx);
  k_gather<<<512, 256, 0, stream>>>(src, trg, cur, idx, sum_s, sum_t, cnt_s, cnt_t);
  k_u<<<CC, 256, 0, stream>>>(sum_s, sum_t, cnt_s, cnt_t, Upk, wcol);
  k_main<<<512, 1024, 0, stream>>>(src, trg, Upk, wcol, out);
}

// Round 16
// 72.283 us; speedup vs baseline: 1.8070x; 1.1459x over previous
//
#include <hip/hip_runtime.h>
#include <hip/hip_bf16.h>

#define NN 16384
#define DD 512
#define CC 256
#define CAP 192

typedef short bf16x8 __attribute__((ext_vector_type(8)));
typedef short bf16x4 __attribute__((ext_vector_type(4)));
typedef float f32x4 __attribute__((ext_vector_type(4)));
typedef float f32x16 __attribute__((ext_vector_type(16)));

__device__ __forceinline__ short f2bf(float x) {
  __hip_bfloat16 h = __float2bfloat16(x);
  return __builtin_bit_cast(short, h);
}

// 32768 rows -> per-(tensor,class) index lists. grid 128 x 256.
__global__ void k_bucket(const int* __restrict__ lab_s, const int* __restrict__ lab_t,
                         int* __restrict__ cur, int* __restrict__ idx) {
  const int i = blockIdx.x * 256 + threadIdx.x;
  const int t = i >> 14, r = i & 16383;
  const int c = (t ? lab_t : lab_s)[r];
  const int tc = t * 256 + c;
  const int pos = atomicAdd(&cur[tc], 1);
  if (pos < CAP) idx[tc * CAP + pos] = r;
}

// grid 512 (one block per (tensor,class)), 256 threads, f32x4 16B/lane.
__global__ void k_gather(const float* __restrict__ src, const float* __restrict__ trg,
                         const int* __restrict__ cur, const int* __restrict__ idx,
                         float* __restrict__ sum_s, float* __restrict__ sum_t,
                         float* __restrict__ cnt_s, float* __restrict__ cnt_t) {
  const int tc = blockIdx.x;
  const int t = tc >> 8, c = tc & 255;
  const float* feat = t ? trg : src;
  float* sum = t ? sum_t : sum_s;
  float* cnt = t ? cnt_t : cnt_s;
  const int tid = threadIdx.x;
  const int q = tid & 127, h = tid >> 7;
  const int count = min(cur[tc], CAP);

  __shared__ int lidx[CAP];
  __shared__ f32x4 sh[128];
  if (tid < count) lidx[tid] = idx[tc * CAP + tid];
  __syncthreads();

  f32x4 a = (f32x4){0.f, 0.f, 0.f, 0.f};
  f32x4 b = (f32x4){0.f, 0.f, 0.f, 0.f};
  int r = h;
  for (; r + 2 < count; r += 4) {
    a += *reinterpret_cast<const f32x4*>(feat + (size_t)lidx[r] * DD + q * 4);
    b += *reinterpret_cast<const f32x4*>(feat + (size_t)lidx[r + 2] * DD + q * 4);
  }
  if (r < count)
    a += *reinterpret_cast<const f32x4*>(feat + (size_t)lidx[r] * DD + q * 4);
  a += b;
  if (h == 1) sh[q] = a;
  __syncthreads();
  if (h == 0) {
    a += sh[q];
    *reinterpret_cast<f32x4*>(sum + c * DD + q * 4) = a;
    if (tid == 0) cnt[c] = (float)count;
  }
}

// grid = 256 (class/col), 256 threads.  Packs u_s, u_t in 32x32x16 B-fragment
// order (u_st is a per-column linear combo reconstructed in k_main):
// e = kc*8192 + t32*1024 + ks*512 + (col31 + 32*hi)*8 + j.  w[c] = cs/(cs+ct).
__global__ void k_u(const float* __restrict__ sum_s, const float* __restrict__ sum_t,
                    const float* __restrict__ cnt_s, const float* __restrict__ cnt_t,
                    unsigned short* __restrict__ Upk, float* __restrict__ wcol) {
  const int c = blockIdx.x, tid = threadIdx.x;
  const float cs = cnt_s[c], ct = cnt_t[c];
  const float rs = 1.f / cs, rt = 1.f / ct;
  const int t32 = c >> 5, col31 = c & 31;
#pragma unroll
  for (int kk = 0; kk < 2; ++kk) {
    const int k = tid + kk * 256;
    const float ss = sum_s[c * DD + k], st = sum_t[c * DD + k];
    const int kc = k >> 5, ks = (k >> 4) & 1, hi = (k >> 3) & 1, j = k & 7;
    const int e = kc * 8192 + t32 * 1024 + ks * 512 + (col31 + 32 * hi) * 8 + j;
    Upk[0 * 131072 + e] = (unsigned short)f2bf(ss * rs);
    Upk[1 * 131072 + e] = (unsigned short)f2bf(st * rt);
  }
  if (tid == 0) wcol[c] = cs / (cs + ct);
}

// grid = 256 blocks (1 per CU, SINGLE pass), 1024 threads (16 waves:
// wr=w>>2 rowtile of 32 rows, cw=w&3 -> 2 col-tiles of 32 per mat).
// Block: 128 rows x (256 cols x 2 mats). acc = 2x2 f32x16 = 64 AGPR.
// Per wave per chunk: 2 A + 8 B ds_read_b128, 8 MFMA; 2 gload_lds + 1 float4.
// R12 single-barrier dbuf pipeline; L_st = w*L_s + (1-w)*L_t (exact identity).
__global__ __launch_bounds__(1024, 4) void k_main(
    const float* __restrict__ src, const float* __restrict__ trg,
    const unsigned short* __restrict__ Upk, const float* __restrict__ wcol,
    float* __restrict__ out) {
  __shared__ short SMEM[40960];    // 80KB: Bs [0,32768), As [32768,40960)
  __shared__ float sLse[3][128];
  __shared__ float bred[16];
  short* const Bs0 = &SMEM[0];
  short* const As0 = &SMEM[32768];

  const int tid = threadIdx.x;
  const int w = tid >> 6, lane = tid & 63;
  const int hi = lane >> 5, l31 = lane & 31;
  const int wr = w >> 2, cw = w & 3;
  const int row0 = blockIdx.x * 128;
  const float* feat = (row0 < NN) ? src + (size_t)row0 * DD
                                  : trg + (size_t)(row0 - NN) * DD;

  // A staging: thread -> (row ar 0..127, float4 slot aq 0..7)
  const int ar = tid >> 3, aq = tid & 7;
  const float* aglob = feat + (size_t)ar * DD + aq * 4;
  const int k0 = aq * 4;
  const int awoff = (ar >> 5) * 1024 + (k0 >> 4) * 512 +
                    ((ar & 31) + 32 * ((k0 >> 3) & 1)) * 8 + (k0 & 7);

  f32x16 acc[2][2];
#pragma unroll
  for (int m = 0; m < 2; ++m)
#pragma unroll
    for (int ct = 0; ct < 2; ++ct)
#pragma unroll
      for (int r = 0; r < 16; ++r) acc[m][ct][r] = 0.f;

  auto stageB = [&](int kc, int buf) {
#pragma unroll
    for (int s = 0; s < 2; ++s) {
      const int u = s * 16 + w;   // 32 units: mat = u>>4, (t32,ks) = u&15
      const unsigned short* g =
          Upk + (size_t)(u >> 4) * 131072 + kc * 8192 + (u & 15) * 512 + lane * 8;
      __builtin_amdgcn_global_load_lds(
          (const __attribute__((address_space(1))) unsigned int*)g,
          (__attribute__((address_space(3))) unsigned int*)&Bs0[buf * 16384 + u * 512],
          16, 0, 0);
    }
  };
  auto writeA = [&](const float4& v, int buf) {
    bf16x4 b;
    b[0] = f2bf(v.x); b[1] = f2bf(v.y); b[2] = f2bf(v.z); b[3] = f2bf(v.w);
    *reinterpret_cast<bf16x4*>(&As0[buf * 4096 + awoff]) = b;
  };
  auto compute = [&](int buf) {
    const bf16x8 a0 = *reinterpret_cast<const bf16x8*>(
        &As0[buf * 4096 + wr * 1024 + 0 * 512 + lane * 8]);
    const bf16x8 a1 = *reinterpret_cast<const bf16x8*>(
        &As0[buf * 4096 + wr * 1024 + 1 * 512 + lane * 8]);
#pragma unroll
    for (int m = 0; m < 2; ++m)
#pragma unroll
      for (int ct = 0; ct < 2; ++ct) {
        const int t32 = cw * 2 + ct;
        const bf16x8 b0 = *reinterpret_cast<const bf16x8*>(
            &Bs0[buf * 16384 + (m * 16 + t32 * 2 + 0) * 512 + lane * 8]);
        const bf16x8 b1 = *reinterpret_cast<const bf16x8*>(
            &Bs0[buf * 16384 + (m * 16 + t32 * 2 + 1) * 512 + lane * 8]);
        acc[m][ct] = __builtin_amdgcn_mfma_f32_32x32x16_bf16(a0, b0, acc[m][ct], 0, 0, 0);
        acc[m][ct] = __builtin_amdgcn_mfma_f32_32x32x16_bf16(a1, b1, acc[m][ct], 0, 0, 0);
      }
  };

  // ---- prologue ----
  float4 af = *reinterpret_cast<const float4*>(aglob);   // A(0)
  asm volatile("" ::: "memory");
  stageB(0, 0);
  writeA(af, 0);

#pragma unroll 1
  for (int kc = 0; kc < 16; ++kc) {
    asm volatile("s_waitcnt vmcnt(0) lgkmcnt(0)" ::: "memory");
    if (kc < 15)
      af = *reinterpret_cast<const float4*>(aglob + (kc + 1) * 32);
    __builtin_amdgcn_s_barrier();
    if (kc < 15) stageB(kc + 1, (kc + 1) & 1);
    compute(kc & 1);
    if (kc < 15) writeA(af, (kc + 1) & 1);
  }

  // ---- epilogue ----
  // C/D layout: col = l31 (of tile cw*2+ct), row = wr*32 + (r&3)+8*(r>>2)+4*hi.
  // L_st = w*L_s + (1-w)*L_t (exact). LSE without max pass (|logit| << 80).
  const float wv0 = wcol[(cw * 2 + 0) * 32 + l31];
  const float wv1 = wcol[(cw * 2 + 1) * 32 + l31];
  f32x16 ca0, ca1;
#pragma unroll
  for (int r = 0; r < 16; ++r) {
    ca0[r] = wv0 * acc[0][0][r] + (1.f - wv0) * acc[1][0][r];
    ca1[r] = wv1 * acc[0][1][r] + (1.f - wv1) * acc[1][1][r];
  }

  __syncthreads();
  float* T = (float*)&SMEM[0];     // 64 x 260 floats = 66.6 KB <= 80 KB
  const int erow = tid >> 4, ecc = tid & 15;

  // 128 rows processed in 2 halves of 64 (rowtiles {0,1} then {2,3})
  auto lsePass = [&](const f32x16& vA, const f32x16& vB, int m) {
#pragma unroll
    for (int h = 0; h < 2; ++h) {
      if ((wr >> 1) == h) {
        const int lr0 = (wr & 1) * 32;
#pragma unroll
        for (int r = 0; r < 16; ++r) {
          const int lr = lr0 + (r & 3) + 8 * (r >> 2) + 4 * hi;
          T[lr * 260 + (cw * 2 + 0) * 32 + l31] = vA[r];
          T[lr * 260 + (cw * 2 + 1) * 32 + l31] = vB[r];
        }
      }
      __syncthreads();
      float s = 0.f;
      const float* tb = &T[erow * 260 + ecc * 16];
#pragma unroll
      for (int j = 0; j < 4; ++j) {
        const f32x4 x = *reinterpret_cast<const f32x4*>(tb + j * 4);
        s += __expf(x[0]) + __expf(x[1]) + __expf(x[2]) + __expf(x[3]);
      }
      s += __shfl_xor(s, 1); s += __shfl_xor(s, 2);
      s += __shfl_xor(s, 4); s += __shfl_xor(s, 8);
      if (ecc == 0) sLse[m][h * 64 + erow] = __logf(s);
      __syncthreads();
    }
  };
  lsePass(acc[0][0], acc[0][1], 0);
  lsePass(acc[1][0], acc[1][1], 1);
  lsePass(ca0, ca1, 2);

  // fused symmetric-KL: sum of e^a(2a-b-c) + e^b(2b-a-c) + e^c(2c-a-b)
  float ks = 0.f;
#pragma unroll
  for (int r = 0; r < 16; ++r) {
    const int row = wr * 32 + (r & 3) + 8 * (r >> 2) + 4 * hi;
    {
      const float a = acc[0][0][r] - sLse[0][row];
      const float b = acc[1][0][r] - sLse[1][row];
      const float c = ca0[r] - sLse[2][row];
      ks += __expf(a) * (2.f * a - b - c) + __expf(b) * (2.f * b - a - c) +
            __expf(c) * (2.f * c - a - b);
    }
    {
      const float a = acc[0][1][r] - sLse[0][row];
      const float b = acc[1][1][r] - sLse[1][row];
      const float c = ca1[r] - sLse[2][row];
      ks += __expf(a) * (2.f * a - b - c) + __expf(b) * (2.f * b - a - c) +
            __expf(c) * (2.f * c - a - b);
    }
  }
#pragma unroll
  for (int off = 1; off < 64; off <<= 1)
    ks += __shfl_xor(ks, off);
  if (lane == 0) bred[w] = ks;
  __syncthreads();
  if (tid == 0) {
    float s = 0.f;
#pragma unroll
    for (int i = 0; i < 16; ++i) s += bred[i];
    atomicAdd(out, s * (1.f / 50331648.f));  // 1/(6 * 2N * C)
  }
}

extern "C" void kernel_launch(void* const* d_in, const int* in_sizes, int n_in,
                              void* d_out, int out_size, void* d_ws, size_t ws_size,
                              hipStream_t stream) {
  const float* src = (const float*)d_in[0];
  const float* trg = (const float*)d_in[1];
  const int* lab_s = (const int*)d_in[2];
  const int* lab_t = (const int*)d_in[3];
  float* out = (float*)d_out;

  char* p = (char*)d_ws;
  float* sum_s = (float*)p;                  p += 524288;
  float* sum_t = (float*)p;                  p += 524288;
  float* cnt_s = (float*)p;                  p += 1024;
  float* cnt_t = (float*)p;                  p += 1024;
  int* cur = (int*)p;                        p += 2048;
  int* idx = (int*)p;                        p += 512 * CAP * 4;
  unsigned short* Upk = (unsigned short*)p;  p += 2 * 131072 * 2;
  float* wcol = (float*)p;                   p += 1024;

  hipMemsetAsync(cur, 0, 2048, stream);
  hipMemsetAsync(out, 0, (size_t)out_size * sizeof(float), stream);
  k_bucket<<<128, 256, 0, stream>>>(lab_s, lab_t, cur, idx);
  k_gather<<<512, 256, 0, stream>>>(src, trg, cur, idx, sum_s, sum_t, cnt_s, cnt_t);
  k_u<<<CC, 256, 0, stream>>>(sum_s, sum_t, cnt_s, cnt_t, Upk, wcol);
  k_main<<<256, 1024, 0, stream>>>(src, trg, Upk, wcol, out);
}

// Round 17
// 69.889 us; speedup vs baseline: 1.8689x; 1.0342x over previous
//
#include <hip/hip_runtime.h>
#include <hip/hip_bf16.h>

#define NN 16384
#define DD 512
#define CC 256
#define CAP 192

typedef short bf16x8 __attribute__((ext_vector_type(8)));
typedef float f32x4 __attribute__((ext_vector_type(4)));
typedef float f32x16 __attribute__((ext_vector_type(16)));

__device__ __forceinline__ short f2bf(float x) {
  __hip_bfloat16 h = __float2bfloat16(x);
  return __builtin_bit_cast(short, h);
}

// 32768 rows -> per-(tensor,class) index lists. grid 128 x 256.
__global__ void k_bucket(const int* __restrict__ lab_s, const int* __restrict__ lab_t,
                         int* __restrict__ cur, int* __restrict__ idx) {
  const int i = blockIdx.x * 256 + threadIdx.x;
  const int t = i >> 14, r = i & 16383;
  const int c = (t ? lab_t : lab_s)[r];
  const int tc = t * 256 + c;
  const int pos = atomicAdd(&cur[tc], 1);
  if (pos < CAP) idx[tc * CAP + pos] = r;
}

// grid 512 (one block per (tensor,class)), 256 threads, f32x4 16B/lane.
__global__ void k_gather(const float* __restrict__ src, const float* __restrict__ trg,
                         const int* __restrict__ cur, const int* __restrict__ idx,
                         float* __restrict__ sum_s, float* __restrict__ sum_t,
                         float* __restrict__ cnt_s, float* __restrict__ cnt_t) {
  const int tc = blockIdx.x;
  const int t = tc >> 8, c = tc & 255;
  const float* feat = t ? trg : src;
  float* sum = t ? sum_t : sum_s;
  float* cnt = t ? cnt_t : cnt_s;
  const int tid = threadIdx.x;
  const int q = tid & 127, h = tid >> 7;
  const int count = min(cur[tc], CAP);

  __shared__ int lidx[CAP];
  __shared__ f32x4 sh[128];
  if (tid < count) lidx[tid] = idx[tc * CAP + tid];
  __syncthreads();

  f32x4 a = (f32x4){0.f, 0.f, 0.f, 0.f};
  f32x4 b = (f32x4){0.f, 0.f, 0.f, 0.f};
  int r = h;
  for (; r + 2 < count; r += 4) {
    a += *reinterpret_cast<const f32x4*>(feat + (size_t)lidx[r] * DD + q * 4);
    b += *reinterpret_cast<const f32x4*>(feat + (size_t)lidx[r + 2] * DD + q * 4);
  }
  if (r < count)
    a += *reinterpret_cast<const f32x4*>(feat + (size_t)lidx[r] * DD + q * 4);
  a += b;
  if (h == 1) sh[q] = a;
  __syncthreads();
  if (h == 0) {
    a += sh[q];
    *reinterpret_cast<f32x4*>(sum + c * DD + q * 4) = a;
    if (tid == 0) cnt[c] = (float)count;
  }
}

// grid = 256 (class/col), 256 threads.  Packs u_s, u_t in 32x32x16 B-fragment
// order (u_st is a per-column linear combo reconstructed in k_main):
// e = kc*8192 + t32*1024 + ks*512 + (col31 + 32*hi)*8 + j.  w[c] = cs/(cs+ct).
__global__ void k_u(const float* __restrict__ sum_s, const float* __restrict__ sum_t,
                    const float* __restrict__ cnt_s, const float* __restrict__ cnt_t,
                    unsigned short* __restrict__ Upk, float* __restrict__ wcol) {
  const int c = blockIdx.x, tid = threadIdx.x;
  const float cs = cnt_s[c], ct = cnt_t[c];
  const float rs = 1.f / cs, rt = 1.f / ct;
  const int t32 = c >> 5, col31 = c & 31;
#pragma unroll
  for (int kk = 0; kk < 2; ++kk) {
    const int k = tid + kk * 256;
    const float ss = sum_s[c * DD + k], st = sum_t[c * DD + k];
    const int kc = k >> 5, ks = (k >> 4) & 1, hi = (k >> 3) & 1, j = k & 7;
    const int e = kc * 8192 + t32 * 1024 + ks * 512 + (col31 + 32 * hi) * 8 + j;
    Upk[0 * 131072 + e] = (unsigned short)f2bf(ss * rs);
    Upk[1 * 131072 + e] = (unsigned short)f2bf(st * rt);
  }
  if (tid == 0) wcol[c] = cs / (cs + ct);
}

// grid = 256 blocks (1 per CU, single pass), 1024 threads (16 waves:
// wr=w>>2 rowtile of 32 rows, cw=w&3 -> 2 col-tiles of 32 per mat).
// Block: 128 rows x (256 cols x 2 mats).  BK=64: 8 chunk-steps.
// LDS = Bs 2x64KB + As 2x16KB = 160KB exactly; epilogue aliases Bs region.
// Per wave per step: 4 B-gload_lds + 2 A-float4 = 6 VMEM, 20 ds_read_b128,
// 16 MFMA; A write is a single ds_write_b128. R12 single-barrier pipeline.
__global__ __launch_bounds__(1024, 4) void k_main(
    const float* __restrict__ src, const float* __restrict__ trg,
    const unsigned short* __restrict__ Upk, const float* __restrict__ wcol,
    float* __restrict__ out) {
  __shared__ short SMEM[81920];    // 160KB: Bs [0,65536), As [65536,81920)
  short* const Bs0 = &SMEM[0];        // 2 bufs x 32768 shorts
  short* const As0 = &SMEM[65536];    // 2 bufs x 8192 shorts

  const int tid = threadIdx.x;
  const int w = tid >> 6, lane = tid & 63;
  const int hi = lane >> 5, l31 = lane & 31;
  const int wr = w >> 2, cw = w & 3;
  const int row0 = blockIdx.x * 128;
  const float* feat = (row0 < NN) ? src + (size_t)row0 * DD
                                  : trg + (size_t)(row0 - NN) * DD;

  // A staging: thread -> (row ar 0..127, 8-float slot q 0..7)
  const int ar = tid >> 3, aq = tid & 7;
  const float* aglob = feat + (size_t)ar * DD + aq * 8;
  const int kcs = aq >> 2, q4 = aq & 3;
  // within 8192-short As buffer (k = kcs*32 + q4*8):
  const int awoff = kcs * 4096 + (ar >> 5) * 1024 + (q4 >> 1) * 512 +
                    ((ar & 31) + 32 * (q4 & 1)) * 8;

  f32x16 acc[2][2];
#pragma unroll
  for (int m = 0; m < 2; ++m)
#pragma unroll
    for (int ct = 0; ct < 2; ++ct)
#pragma unroll
      for (int r = 0; r < 16; ++r) acc[m][ct][r] = 0.f;

  auto stageB = [&](int kc8, int buf) {
#pragma unroll
    for (int s = 0; s < 4; ++s) {
      const int u = s * 16 + w;   // u = kcs*32 + mat*16 + tile16
      const int uk = u >> 5, mat = (u >> 4) & 1, t16 = u & 15;
      const unsigned short* g = Upk + (size_t)mat * 131072 +
                                (kc8 * 2 + uk) * 8192 + t16 * 512 + lane * 8;
      __builtin_amdgcn_global_load_lds(
          (const __attribute__((address_space(1))) unsigned int*)g,
          (__attribute__((address_space(3))) unsigned int*)&Bs0[buf * 32768 + u * 512],
          16, 0, 0);
    }
  };
  auto writeA = [&](const float4& v0, const float4& v1, int buf) {
    bf16x8 b;
    b[0] = f2bf(v0.x); b[1] = f2bf(v0.y); b[2] = f2bf(v0.z); b[3] = f2bf(v0.w);
    b[4] = f2bf(v1.x); b[5] = f2bf(v1.y); b[6] = f2bf(v1.z); b[7] = f2bf(v1.w);
    *reinterpret_cast<bf16x8*>(&As0[buf * 8192 + awoff]) = b;
  };
  auto compute = [&](int buf) {
#pragma unroll
    for (int kk = 0; kk < 2; ++kk) {   // sub-chunk of 32 k
      const bf16x8 a0 = *reinterpret_cast<const bf16x8*>(
          &As0[buf * 8192 + kk * 4096 + wr * 1024 + 0 * 512 + lane * 8]);
      const bf16x8 a1 = *reinterpret_cast<const bf16x8*>(
          &As0[buf * 8192 + kk * 4096 + wr * 1024 + 1 * 512 + lane * 8]);
#pragma unroll
      for (int m = 0; m < 2; ++m)
#pragma unroll
        for (int ct = 0; ct < 2; ++ct) {
          const int t32 = cw * 2 + ct;
          const bf16x8 b0 = *reinterpret_cast<const bf16x8*>(
              &Bs0[buf * 32768 + kk * 16384 + (m * 16 + t32 * 2 + 0) * 512 + lane * 8]);
          const bf16x8 b1 = *reinterpret_cast<const bf16x8*>(
              &Bs0[buf * 32768 + kk * 16384 + (m * 16 + t32 * 2 + 1) * 512 + lane * 8]);
          acc[m][ct] = __builtin_amdgcn_mfma_f32_32x32x16_bf16(a0, b0, acc[m][ct], 0, 0, 0);
          acc[m][ct] = __builtin_amdgcn_mfma_f32_32x32x16_bf16(a1, b1, acc[m][ct], 0, 0, 0);
        }
    }
  };

  // ---- prologue ----
  float4 af0 = *reinterpret_cast<const float4*>(aglob);       // A(0)
  float4 af1 = *reinterpret_cast<const float4*>(aglob + 4);
  asm volatile("" ::: "memory");
  stageB(0, 0);
  writeA(af0, af1, 0);   // implicit wait: A(0) only (oldest in FIFO)

#pragma unroll 1
  for (int kc8 = 0; kc8 < 8; ++kc8) {
    asm volatile("s_waitcnt vmcnt(0) lgkmcnt(0)" ::: "memory");
    if (kc8 < 7) {
      af0 = *reinterpret_cast<const float4*>(aglob + (kc8 + 1) * 64);
      af1 = *reinterpret_cast<const float4*>(aglob + (kc8 + 1) * 64 + 4);
    }
    __builtin_amdgcn_s_barrier();
    if (kc8 < 7) stageB(kc8 + 1, (kc8 + 1) & 1);
    compute(kc8 & 1);
    if (kc8 < 7) writeA(af0, af1, (kc8 + 1) & 1);  // waits af only; B flies
  }

  // ---- epilogue ----
  // C/D layout: col = l31 (of tile cw*2+ct), row = wr*32 + (r&3)+8*(r>>2)+4*hi.
  // L_st = w*L_s + (1-w)*L_t (exact). LSE without max pass (|logit| << 80).
  const float wv0 = wcol[(cw * 2 + 0) * 32 + l31];
  const float wv1 = wcol[(cw * 2 + 1) * 32 + l31];
  f32x16 ca0, ca1;
#pragma unroll
  for (int r = 0; r < 16; ++r) {
    ca0[r] = wv0 * acc[0][0][r] + (1.f - wv0) * acc[1][0][r];
    ca1[r] = wv1 * acc[0][1][r] + (1.f - wv1) * acc[1][1][r];
  }

  __syncthreads();
  float* T = (float*)&SMEM[0];       // 64 x 260 floats = 66.6 KB
  float* sLseF = T + 16640;          // [3][128] floats (aliases SMEM tail)
  float* bredF = T + 17024;          // [16] floats
  const int erow = tid >> 4, ecc = tid & 15;

  // 128 rows processed in 2 halves of 64 (rowtiles {0,1} then {2,3})
  auto lsePass = [&](const f32x16& vA, const f32x16& vB, int m) {
#pragma unroll
    for (int h = 0; h < 2; ++h) {
      if ((wr >> 1) == h) {
        const int lr0 = (wr & 1) * 32;
#pragma unroll
        for (int r = 0; r < 16; ++r) {
          const int lr = lr0 + (r & 3) + 8 * (r >> 2) + 4 * hi;
          T[lr * 260 + (cw * 2 + 0) * 32 + l31] = vA[r];
          T[lr * 260 + (cw * 2 + 1) * 32 + l31] = vB[r];
        }
      }
      __syncthreads();
      float s = 0.f;
      const float* tb = &T[erow * 260 + ecc * 16];
#pragma unroll
      for (int j = 0; j < 4; ++j) {
        const f32x4 x = *reinterpret_cast<const f32x4*>(tb + j * 4);
        s += __expf(x[0]) + __expf(x[1]) + __expf(x[2]) + __expf(x[3]);
      }
      s += __shfl_xor(s, 1); s += __shfl_xor(s, 2);
      s += __shfl_xor(s, 4); s += __shfl_xor(s, 8);
      if (ecc == 0) sLseF[m * 128 + h * 64 + erow] = __logf(s);
      __syncthreads();
    }
  };
  lsePass(acc[0][0], acc[0][1], 0);
  lsePass(acc[1][0], acc[1][1], 1);
  lsePass(ca0, ca1, 2);

  // fused symmetric-KL: sum of e^a(2a-b-c) + e^b(2b-a-c) + e^c(2c-a-b)
  float ks = 0.f;
#pragma unroll
  for (int r = 0; r < 16; ++r) {
    const int row = wr * 32 + (r & 3) + 8 * (r >> 2) + 4 * hi;
    {
      const float a = acc[0][0][r] - sLseF[row];
      const float b = acc[1][0][r] - sLseF[128 + row];
      const float c = ca0[r] - sLseF[256 + row];
      ks += __expf(a) * (2.f * a - b - c) + __expf(b) * (2.f * b - a - c) +
            __expf(c) * (2.f * c - a - b);
    }
    {
      const float a = acc[0][1][r] - sLseF[row];
      const float b = acc[1][1][r] - sLseF[128 + row];
      const float c = ca1[r] - sLseF[256 + row];
      ks += __expf(a) * (2.f * a - b - c) + __expf(b) * (2.f * b - a - c) +
            __expf(c) * (2.f * c - a - b);
    }
  }
#pragma unroll
  for (int off = 1; off < 64; off <<= 1)
    ks += __shfl_xor(ks, off);
  if (lane == 0) bredF[w] = ks;
  __syncthreads();
  if (tid == 0) {
    float s = 0.f;
#pragma unroll
    for (int i = 0; i < 16; ++i) s += bredF[i];
    atomicAdd(out, s * (1.f / 50331648.f));  // 1/(6 * 2N * C)
  }
}

extern "C" void kernel_launch(void* const* d_in, const int* in_sizes, int n_in,
                              void* d_out, int out_size, void* d_ws, size_t ws_size,
                              hipStream_t stream) {
  const float* src = (const float*)d_in[0];
  const float* trg = (const float*)d_in[1];
  const int* lab_s = (const int*)d_in[2];
  const int* lab_t = (const int*)d_in[3];
  float* out = (float*)d_out;

  char* p = (char*)d_ws;
  float* sum_s = (float*)p;                  p += 524288;
  float* sum_t = (float*)p;                  p += 524288;
  float* cnt_s = (float*)p;                  p += 1024;
  float* cnt_t = (float*)p;                  p += 1024;
  int* cur = (int*)p;                        p += 2048;
  int* idx = (int*)p;                        p += 512 * CAP * 4;
  unsigned short* Upk = (unsigned short*)p;  p += 2 * 131072 * 2;
  float* wcol = (float*)p;                   p += 1024;

  hipMemsetAsync(cur, 0, 2048, stream);
  hipMemsetAsync(out, 0, (size_t)out_size * sizeof(float), stream);
  k_bucket<<<128, 256, 0, stream>>>(lab_s, lab_t, cur, idx);
  k_gather<<<512, 256, 0, stream>>>(src, trg, cur, idx, sum_s, sum_t, cnt_s, cnt_t);
  k_u<<<CC, 256, 0, stream>>>(sum_s, sum_t, cnt_s, cnt_t, Upk, wcol);
  k_main<<<256, 1024, 0, stream>>>(src, trg, Upk, wcol, out);
}

// Round 18
// 66.103 us; speedup vs baseline: 1.9759x; 1.0573x over previous
//
#include <hip/hip_runtime.h>
#include <hip/hip_bf16.h>

#define NN 16384
#define DD 512
#define CC 256
#define CAP 192

typedef short bf16x8 __attribute__((ext_vector_type(8)));
typedef short bf16x4 __attribute__((ext_vector_type(4)));
typedef float f32x4 __attribute__((ext_vector_type(4)));
typedef float f32x16 __attribute__((ext_vector_type(16)));

__device__ __forceinline__ short f2bf(float x) {
  __hip_bfloat16 h = __float2bfloat16(x);
  return __builtin_bit_cast(short, h);
}

// 32768 rows -> per-(tensor,class) index lists. grid 128 x 256. Also zeros out.
__global__ void k_bucket(const int* __restrict__ lab_s, const int* __restrict__ lab_t,
                         int* __restrict__ cur, int* __restrict__ idx,
                         float* __restrict__ out) {
  const int i = blockIdx.x * 256 + threadIdx.x;
  if (i == 0) *out = 0.f;
  const int t = i >> 14, r = i & 16383;
  const int c = (t ? lab_t : lab_s)[r];
  const int tc = t * 256 + c;
  const int pos = atomicAdd(&cur[tc], 1);
  if (pos < CAP) idx[tc * CAP + pos] = r;
}

// grid 512 (one block per (tensor,class)), 256 threads, f32x4 16B/lane.
// FUSED with k_u: writes the class's packed B-fragment rows of Upk directly.
// Pack: e = kc*8192 + t32*1024 + ks*512 + (col31 + 32*hi)*8 + j.
__global__ void k_gather(const float* __restrict__ src, const float* __restrict__ trg,
                         const int* __restrict__ cur, const int* __restrict__ idx,
                         unsigned short* __restrict__ Upk,
                         float* __restrict__ cnt_s, float* __restrict__ cnt_t) {
  const int tc = blockIdx.x;
  const int t = tc >> 8, c = tc & 255;
  const float* feat = t ? trg : src;
  const int tid = threadIdx.x;
  const int q = tid & 127, h = tid >> 7;
  const int count = min(cur[tc], CAP);

  __shared__ int lidx[CAP];
  __shared__ f32x4 sh[128];
  if (tid < count) lidx[tid] = idx[tc * CAP + tid];
  __syncthreads();

  f32x4 a = (f32x4){0.f, 0.f, 0.f, 0.f};
  f32x4 b = (f32x4){0.f, 0.f, 0.f, 0.f};
  int r = h;
  for (; r + 2 < count; r += 4) {
    a += *reinterpret_cast<const f32x4*>(feat + (size_t)lidx[r] * DD + q * 4);
    b += *reinterpret_cast<const f32x4*>(feat + (size_t)lidx[r + 2] * DD + q * 4);
  }
  if (r < count)
    a += *reinterpret_cast<const f32x4*>(feat + (size_t)lidx[r] * DD + q * 4);
  a += b;
  if (h == 1) sh[q] = a;
  __syncthreads();
  if (h == 0) {
    a += sh[q];
    const float inv = 1.f / (float)count;
    const int t32 = c >> 5, col31 = c & 31;
    const int k = q * 4;
    const int kc = k >> 5, ks = (k >> 4) & 1, khi = (k >> 3) & 1, j = k & 7;
    const int e = kc * 8192 + t32 * 1024 + ks * 512 + (col31 + 32 * khi) * 8 + j;
    bf16x4 bb;
    bb[0] = f2bf(a[0] * inv); bb[1] = f2bf(a[1] * inv);
    bb[2] = f2bf(a[2] * inv); bb[3] = f2bf(a[3] * inv);
    *reinterpret_cast<bf16x4*>(&Upk[(size_t)t * 131072 + e]) = bb;
    if (tid == 0) (t ? cnt_t : cnt_s)[c] = (float)count;
  }
}

// grid = 256 blocks (1 per CU, single pass), 1024 threads (16 waves:
// rp=w>>3 row-group of 64 rows (2 rowtiles), t32w=w&7 col-tile of 32, x2 mats).
// Block: 128 rows x (256 cols x 2 mats). BK=64: 8 chunk-steps.
// Config B: per 32-k sub-chunk 4 A + 4 B ds_read_b128 feed 8 MFMA (B reused
// across the 2 rowtiles). acc = 2 mats x 2 rt x f32x16 = 64 AGPR.
// LDS = Bs 2x64KB + As 2x16KB = 160KB; epilogue aliases it.
// L_st = w*L_s + (1-w)*L_t (exact); LSE without max pass (|logit| << 80).
__global__ __launch_bounds__(1024, 4) void k_main(
    const float* __restrict__ src, const float* __restrict__ trg,
    const unsigned short* __restrict__ Upk, const float* __restrict__ cnt_s,
    const float* __restrict__ cnt_t, float* __restrict__ out) {
  __shared__ short SMEM[81920];    // 160KB: Bs [0,65536), As [65536,81920)
  short* const Bs0 = &SMEM[0];        // 2 bufs x 32768 shorts
  short* const As0 = &SMEM[65536];    // 2 bufs x 8192 shorts

  const int tid = threadIdx.x;
  const int w = tid >> 6, lane = tid & 63;
  const int hi = lane >> 5, l31 = lane & 31;
  const int rp = w >> 3, t32w = w & 7;
  const int row0 = blockIdx.x * 128;
  const float* feat = (row0 < NN) ? src + (size_t)row0 * DD
                                  : trg + (size_t)(row0 - NN) * DD;

  // A staging: thread -> (row ar 0..127, 8-float slot aq 0..7)
  const int ar = tid >> 3, aq = tid & 7;
  const float* aglob = feat + (size_t)ar * DD + aq * 8;
  const int kcs = aq >> 2, q4 = aq & 3;
  const int awoff = kcs * 4096 + (ar >> 5) * 1024 + (q4 >> 1) * 512 +
                    ((ar & 31) + 32 * (q4 & 1)) * 8;

  f32x16 acc[2][2];   // [mat][rowtile]
#pragma unroll
  for (int m = 0; m < 2; ++m)
#pragma unroll
    for (int rt = 0; rt < 2; ++rt)
#pragma unroll
      for (int r = 0; r < 16; ++r) acc[m][rt][r] = 0.f;

  auto stageB = [&](int kc8, int buf) {
#pragma unroll
    for (int s = 0; s < 4; ++s) {
      const int u = s * 16 + w;   // u = uk*32 + mat*16 + t16
      const int uk = u >> 5, mat = (u >> 4) & 1, t16 = u & 15;
      const unsigned short* g = Upk + (size_t)mat * 131072 +
                                (kc8 * 2 + uk) * 8192 + t16 * 512 + lane * 8;
      __builtin_amdgcn_global_load_lds(
          (const __attribute__((address_space(1))) unsigned int*)g,
          (__attribute__((address_space(3))) unsigned int*)&Bs0[buf * 32768 + u * 512],
          16, 0, 0);
    }
  };
  auto writeA = [&](const float4& v0, const float4& v1, int buf) {
    bf16x8 b;
    b[0] = f2bf(v0.x); b[1] = f2bf(v0.y); b[2] = f2bf(v0.z); b[3] = f2bf(v0.w);
    b[4] = f2bf(v1.x); b[5] = f2bf(v1.y); b[6] = f2bf(v1.z); b[7] = f2bf(v1.w);
    *reinterpret_cast<bf16x8*>(&As0[buf * 8192 + awoff]) = b;
  };
  auto compute = [&](int buf) {
#pragma unroll
    for (int kk = 0; kk < 2; ++kk) {   // 32-k sub-chunk
      bf16x8 a[2][2];   // [rt][ks]
#pragma unroll
      for (int rt = 0; rt < 2; ++rt)
#pragma unroll
        for (int ks = 0; ks < 2; ++ks)
          a[rt][ks] = *reinterpret_cast<const bf16x8*>(
              &As0[buf * 8192 + kk * 4096 + (rp * 2 + rt) * 1024 + ks * 512 + lane * 8]);
#pragma unroll
      for (int m = 0; m < 2; ++m) {
        const bf16x8 b0 = *reinterpret_cast<const bf16x8*>(
            &Bs0[buf * 32768 + kk * 16384 + (m * 16 + t32w * 2 + 0) * 512 + lane * 8]);
        const bf16x8 b1 = *reinterpret_cast<const bf16x8*>(
            &Bs0[buf * 32768 + kk * 16384 + (m * 16 + t32w * 2 + 1) * 512 + lane * 8]);
#pragma unroll
        for (int rt = 0; rt < 2; ++rt) {
          acc[m][rt] = __builtin_amdgcn_mfma_f32_32x32x16_bf16(a[rt][0], b0, acc[m][rt], 0, 0, 0);
          acc[m][rt] = __builtin_amdgcn_mfma_f32_32x32x16_bf16(a[rt][1], b1, acc[m][rt], 0, 0, 0);
        }
      }
    }
  };

  // ---- prologue ----
  float4 af0 = *reinterpret_cast<const float4*>(aglob);       // A(0)
  float4 af1 = *reinterpret_cast<const float4*>(aglob + 4);
  asm volatile("" ::: "memory");
  stageB(0, 0);
  writeA(af0, af1, 0);   // implicit wait: A(0) only (oldest in FIFO)

#pragma unroll 1
  for (int kc8 = 0; kc8 < 8; ++kc8) {
    asm volatile("s_waitcnt vmcnt(0) lgkmcnt(0)" ::: "memory");
    if (kc8 < 7) {
      af0 = *reinterpret_cast<const float4*>(aglob + (kc8 + 1) * 64);
      af1 = *reinterpret_cast<const float4*>(aglob + (kc8 + 1) * 64 + 4);
    }
    __builtin_amdgcn_s_barrier();
    if (kc8 < 7) stageB(kc8 + 1, (kc8 + 1) & 1);
    compute(kc8 & 1);
    if (kc8 < 7) writeA(af0, af1, (kc8 + 1) & 1);  // waits af only; B flies
  }

  // ---- epilogue ----
  // C/D layout: col = t32w*32 + l31, row = rp*64 + rt*32 + (r&3)+8*(r>>2)+4*hi.
  const float csv = cnt_s[t32w * 32 + l31];
  const float ctv = cnt_t[t32w * 32 + l31];
  const float wv = csv / (csv + ctv);
  f32x16 ca[2];
#pragma unroll
  for (int rt = 0; rt < 2; ++rt)
#pragma unroll
    for (int r = 0; r < 16; ++r)
      ca[rt][r] = wv * acc[0][rt][r] + (1.f - wv) * acc[1][rt][r];

  __syncthreads();
  float* T = (float*)&SMEM[0];       // 64 x 260 floats = 66.6 KB
  float* sLseF = T + 16640;          // [3][128]
  float* bredF = T + 17024;          // [16]
  const int erow = tid >> 4, ecc = tid & 15;

  // 128 rows in 2 halves of 64 (half h = row-group rp == h)
  auto lsePass = [&](const f32x16& v0, const f32x16& v1, int m) {
#pragma unroll
    for (int h = 0; h < 2; ++h) {
      if (rp == h) {
#pragma unroll
        for (int r = 0; r < 16; ++r) {
          const int lrb = (r & 3) + 8 * (r >> 2) + 4 * hi;
          T[(0 * 32 + lrb) * 260 + t32w * 32 + l31] = v0[r];
          T[(1 * 32 + lrb) * 260 + t32w * 32 + l31] = v1[r];
        }
      }
      __syncthreads();
      float s = 0.f;
      const float* tb = &T[erow * 260 + ecc * 16];
#pragma unroll
      for (int j = 0; j < 4; ++j) {
        const f32x4 x = *reinterpret_cast<const f32x4*>(tb + j * 4);
        s += __expf(x[0]) + __expf(x[1]) + __expf(x[2]) + __expf(x[3]);
      }
      s += __shfl_xor(s, 1); s += __shfl_xor(s, 2);
      s += __shfl_xor(s, 4); s += __shfl_xor(s, 8);
      if (ecc == 0) sLseF[m * 128 + h * 64 + erow] = __logf(s);
      __syncthreads();
    }
  };
  lsePass(acc[0][0], acc[0][1], 0);
  lsePass(acc[1][0], acc[1][1], 1);
  lsePass(ca[0], ca[1], 2);

  // fused symmetric-KL: sum of e^a(2a-b-c) + e^b(2b-a-c) + e^c(2c-a-b)
  float ks = 0.f;
#pragma unroll
  for (int rt = 0; rt < 2; ++rt)
#pragma unroll
    for (int r = 0; r < 16; ++r) {
      const int row = rp * 64 + rt * 32 + (r & 3) + 8 * (r >> 2) + 4 * hi;
      const float a = acc[0][rt][r] - sLseF[row];
      const float b = acc[1][rt][r] - sLseF[128 + row];
      const float c = ca[rt][r] - sLseF[256 + row];
      ks += __expf(a) * (2.f * a - b - c) + __expf(b) * (2.f * b - a - c) +
            __expf(c) * (2.f * c - a - b);
    }
#pragma unroll
  for (int off = 1; off < 64; off <<= 1)
    ks += __shfl_xor(ks, off);
  if (lane == 0) bredF[w] = ks;
  __syncthreads();
  if (tid == 0) {
    float s = 0.f;
#pragma unroll
    for (int i = 0; i < 16; ++i) s += bredF[i];
    atomicAdd(out, s * (1.f / 50331648.f));  // 1/(6 * 2N * C)
  }
}

extern "C" void kernel_launch(void* const* d_in, const int* in_sizes, int n_in,
                              void* d_out, int out_size, void* d_ws, size_t ws_size,
                              hipStream_t stream) {
  const float* src = (const float*)d_in[0];
  const float* trg = (const float*)d_in[1];
  const int* lab_s = (const int*)d_in[2];
  const int* lab_t = (const int*)d_in[3];
  float* out = (float*)d_out;

  char* p = (char*)d_ws;
  float* cnt_s = (float*)p;                  p += 1024;
  float* cnt_t = (float*)p;                  p += 1024;
  int* cur = (int*)p;                        p += 2048;
  int* idx = (int*)p;                        p += 512 * CAP * 4;
  unsigned short* Upk = (unsigned short*)p;  p += 2 * 131072 * 2;

  hipMemsetAsync(cur, 0, 2048, stream);
  k_bucket<<<128, 256, 0, stream>>>(lab_s, lab_t, cur, idx, out);
  k_gather<<<512, 256, 0, stream>>>(src, trg, cur, idx, Upk, cnt_s, cnt_t);
  k_main<<<256, 1024, 0, stream>>>(src, trg, Upk, cnt_s, cnt_t, out);
}

// Round 19
// 65.573 us; speedup vs baseline: 1.9919x; 1.0081x over previous
//
#include <hip/hip_runtime.h>
#include <hip/hip_bf16.h>

#define NN 16384
#define DD 512
#define CC 256
#define CAP 192

typedef short bf16x8 __attribute__((ext_vector_type(8)));
typedef short bf16x4 __attribute__((ext_vector_type(4)));
typedef float f32x4 __attribute__((ext_vector_type(4)));
typedef float f32x16 __attribute__((ext_vector_type(16)));

__device__ __forceinline__ short f2bf(float x) {
  __hip_bfloat16 h = __float2bfloat16(x);
  return __builtin_bit_cast(short, h);
}

// 32768 rows -> per-(tensor,class) index lists. grid 128 x 256. Also zeros out.
__global__ void k_bucket(const int* __restrict__ lab_s, const int* __restrict__ lab_t,
                         int* __restrict__ cur, int* __restrict__ idx,
                         float* __restrict__ out) {
  const int i = blockIdx.x * 256 + threadIdx.x;
  if (i == 0) *out = 0.f;
  const int t = i >> 14, r = i & 16383;
  const int c = (t ? lab_t : lab_s)[r];
  const int tc = t * 256 + c;
  const int pos = atomicAdd(&cur[tc], 1);
  if (pos < CAP) idx[tc * CAP + pos] = r;
}

// grid 512 (one block per (tensor,class)), 256 threads, f32x4 16B/lane.
// 8 rows in flight (4 streams x h-split). FUSED with k_u: writes the class's
// packed B-fragment rows of Upk directly.
// Pack: e = kc*8192 + t32*1024 + ks*512 + (col31 + 32*hi)*8 + j.
__global__ void k_gather(const float* __restrict__ src, const float* __restrict__ trg,
                         const int* __restrict__ cur, const int* __restrict__ idx,
                         unsigned short* __restrict__ Upk,
                         float* __restrict__ cnt_s, float* __restrict__ cnt_t) {
  const int tc = blockIdx.x;
  const int t = tc >> 8, c = tc & 255;
  const float* feat = t ? trg : src;
  const int tid = threadIdx.x;
  const int q = tid & 127, h = tid >> 7;
  const int count = min(cur[tc], CAP);

  __shared__ int lidx[CAP];
  __shared__ f32x4 sh[128];
  if (tid < count) lidx[tid] = idx[tc * CAP + tid];
  __syncthreads();

  f32x4 a0 = (f32x4){0.f, 0.f, 0.f, 0.f};
  f32x4 a1 = (f32x4){0.f, 0.f, 0.f, 0.f};
  f32x4 a2 = (f32x4){0.f, 0.f, 0.f, 0.f};
  f32x4 a3 = (f32x4){0.f, 0.f, 0.f, 0.f};
  int r = h;
  for (; r + 6 < count; r += 8) {
    const f32x4 v0 = *reinterpret_cast<const f32x4*>(feat + (size_t)lidx[r] * DD + q * 4);
    const f32x4 v1 = *reinterpret_cast<const f32x4*>(feat + (size_t)lidx[r + 2] * DD + q * 4);
    const f32x4 v2 = *reinterpret_cast<const f32x4*>(feat + (size_t)lidx[r + 4] * DD + q * 4);
    const f32x4 v3 = *reinterpret_cast<const f32x4*>(feat + (size_t)lidx[r + 6] * DD + q * 4);
    a0 += v0; a1 += v1; a2 += v2; a3 += v3;
  }
  for (; r < count; r += 2)
    a0 += *reinterpret_cast<const f32x4*>(feat + (size_t)lidx[r] * DD + q * 4);
  a0 += a1; a2 += a3; a0 += a2;
  if (h == 1) sh[q] = a0;
  __syncthreads();
  if (h == 0) {
    a0 += sh[q];
    const float inv = 1.f / (float)count;
    const int t32 = c >> 5, col31 = c & 15 | (c & 31);  // c & 31
    const int c31 = c & 31;
    const int k = q * 4;
    const int kc = k >> 5, ks = (k >> 4) & 1, khi = (k >> 3) & 1, j = k & 7;
    const int e = kc * 8192 + t32 * 1024 + ks * 512 + (c31 + 32 * khi) * 8 + j;
    bf16x4 bb;
    bb[0] = f2bf(a0[0] * inv); bb[1] = f2bf(a0[1] * inv);
    bb[2] = f2bf(a0[2] * inv); bb[3] = f2bf(a0[3] * inv);
    *reinterpret_cast<bf16x4*>(&Upk[(size_t)t * 131072 + e]) = bb;
    if (tid == 0) (t ? cnt_t : cnt_s)[c] = (float)count;
  }
}

// grid = 256 blocks (1 per CU, single pass), 1024 threads (16 waves:
// rp=w>>3 row-group of 64 rows (2 rowtiles), t32w=w&7 col-tile of 32, x2 mats).
// Block: 128 rows x (256 cols x 2 mats). BK=64: 8 chunk-steps.
// Config B: per 32-k sub-chunk 4 A + 4 B ds_read_b128 feed 8 MFMA (B reused
// across the 2 rowtiles). acc = 2 mats x 2 rt x f32x16 = 64 AGPR.
// LDS = Bs 2x64KB + As 2x16KB = 160KB; epilogue aliases it.
// T5: s_setprio(1) around the MFMA cluster (stage/compute role diversity).
// L_st = w*L_s + (1-w)*L_t (exact); LSE without max pass (|logit| << 80).
__global__ __launch_bounds__(1024, 4) void k_main(
    const float* __restrict__ src, const float* __restrict__ trg,
    const unsigned short* __restrict__ Upk, const float* __restrict__ cnt_s,
    const float* __restrict__ cnt_t, float* __restrict__ out) {
  __shared__ short SMEM[81920];    // 160KB: Bs [0,65536), As [65536,81920)
  short* const Bs0 = &SMEM[0];        // 2 bufs x 32768 shorts
  short* const As0 = &SMEM[65536];    // 2 bufs x 8192 shorts

  const int tid = threadIdx.x;
  const int w = tid >> 6, lane = tid & 63;
  const int hi = lane >> 5, l31 = lane & 31;
  const int rp = w >> 3, t32w = w & 7;
  const int row0 = blockIdx.x * 128;
  const float* feat = (row0 < NN) ? src + (size_t)row0 * DD
                                  : trg + (size_t)(row0 - NN) * DD;

  // A staging: thread -> (row ar 0..127, 8-float slot aq 0..7)
  const int ar = tid >> 3, aq = tid & 7;
  const float* aglob = feat + (size_t)ar * DD + aq * 8;
  const int kcs = aq >> 2, q4 = aq & 3;
  const int awoff = kcs * 4096 + (ar >> 5) * 1024 + (q4 >> 1) * 512 +
                    ((ar & 31) + 32 * (q4 & 1)) * 8;

  f32x16 acc[2][2];   // [mat][rowtile]
#pragma unroll
  for (int m = 0; m < 2; ++m)
#pragma unroll
    for (int rt = 0; rt < 2; ++rt)
#pragma unroll
      for (int r = 0; r < 16; ++r) acc[m][rt][r] = 0.f;

  auto stageB = [&](int kc8, int buf) {
#pragma unroll
    for (int s = 0; s < 4; ++s) {
      const int u = s * 16 + w;   // u = uk*32 + mat*16 + t16
      const int uk = u >> 5, mat = (u >> 4) & 1, t16 = u & 15;
      const unsigned short* g = Upk + (size_t)mat * 131072 +
                                (kc8 * 2 + uk) * 8192 + t16 * 512 + lane * 8;
      __builtin_amdgcn_global_load_lds(
          (const __attribute__((address_space(1))) unsigned int*)g,
          (__attribute__((address_space(3))) unsigned int*)&Bs0[buf * 32768 + u * 512],
          16, 0, 0);
    }
  };
  auto writeA = [&](const float4& v0, const float4& v1, int buf) {
    bf16x8 b;
    b[0] = f2bf(v0.x); b[1] = f2bf(v0.y); b[2] = f2bf(v0.z); b[3] = f2bf(v0.w);
    b[4] = f2bf(v1.x); b[5] = f2bf(v1.y); b[6] = f2bf(v1.z); b[7] = f2bf(v1.w);
    *reinterpret_cast<bf16x8*>(&As0[buf * 8192 + awoff]) = b;
  };
  auto compute = [&](int buf) {
    __builtin_amdgcn_s_setprio(1);
#pragma unroll
    for (int kk = 0; kk < 2; ++kk) {   // 32-k sub-chunk
      bf16x8 a[2][2];   // [rt][ks]
#pragma unroll
      for (int rt = 0; rt < 2; ++rt)
#pragma unroll
        for (int ks = 0; ks < 2; ++ks)
          a[rt][ks] = *reinterpret_cast<const bf16x8*>(
              &As0[buf * 8192 + kk * 4096 + (rp * 2 + rt) * 1024 + ks * 512 + lane * 8]);
#pragma unroll
      for (int m = 0; m < 2; ++m) {
        const bf16x8 b0 = *reinterpret_cast<const bf16x8*>(
            &Bs0[buf * 32768 + kk * 16384 + (m * 16 + t32w * 2 + 0) * 512 + lane * 8]);
        const bf16x8 b1 = *reinterpret_cast<const bf16x8*>(
            &Bs0[buf * 32768 + kk * 16384 + (m * 16 + t32w * 2 + 1) * 512 + lane * 8]);
#pragma unroll
        for (int rt = 0; rt < 2; ++rt) {
          acc[m][rt] = __builtin_amdgcn_mfma_f32_32x32x16_bf16(a[rt][0], b0, acc[m][rt], 0, 0, 0);
          acc[m][rt] = __builtin_amdgcn_mfma_f32_32x32x16_bf16(a[rt][1], b1, acc[m][rt], 0, 0, 0);
        }
      }
    }
    __builtin_amdgcn_s_setprio(0);
  };

  // ---- prologue ----
  float4 af0 = *reinterpret_cast<const float4*>(aglob);       // A(0)
  float4 af1 = *reinterpret_cast<const float4*>(aglob + 4);
  asm volatile("" ::: "memory");
  stageB(0, 0);
  writeA(af0, af1, 0);   // implicit wait: A(0) only (oldest in FIFO)

#pragma unroll 1
  for (int kc8 = 0; kc8 < 8; ++kc8) {
    asm volatile("s_waitcnt vmcnt(0) lgkmcnt(0)" ::: "memory");
    if (kc8 < 7) {
      af0 = *reinterpret_cast<const float4*>(aglob + (kc8 + 1) * 64);
      af1 = *reinterpret_cast<const float4*>(aglob + (kc8 + 1) * 64 + 4);
    }
    __builtin_amdgcn_s_barrier();
    if (kc8 < 7) stageB(kc8 + 1, (kc8 + 1) & 1);
    compute(kc8 & 1);
    if (kc8 < 7) writeA(af0, af1, (kc8 + 1) & 1);  // waits af only; B flies
  }

  // ---- epilogue ----
  // C/D layout: col = t32w*32 + l31, row = rp*64 + rt*32 + (r&3)+8*(r>>2)+4*hi.
  const float csv = cnt_s[t32w * 32 + l31];
  const float ctv = cnt_t[t32w * 32 + l31];
  const float wv = csv / (csv + ctv);
  f32x16 ca[2];
#pragma unroll
  for (int rt = 0; rt < 2; ++rt)
#pragma unroll
    for (int r = 0; r < 16; ++r)
      ca[rt][r] = wv * acc[0][rt][r] + (1.f - wv) * acc[1][rt][r];

  __syncthreads();
  float* T = (float*)&SMEM[0];       // 64 x 260 floats = 66.6 KB
  float* sLseF = T + 16640;          // [3][128]
  float* bredF = T + 17024;          // [16]
  const int erow = tid >> 4, ecc = tid & 15;

  // 128 rows in 2 halves of 64 (half h = row-group rp == h)
  auto lsePass = [&](const f32x16& v0, const f32x16& v1, int m) {
#pragma unroll
    for (int h = 0; h < 2; ++h) {
      if (rp == h) {
#pragma unroll
        for (int r = 0; r < 16; ++r) {
          const int lrb = (r & 3) + 8 * (r >> 2) + 4 * hi;
          T[(0 * 32 + lrb) * 260 + t32w * 32 + l31] = v0[r];
          T[(1 * 32 + lrb) * 260 + t32w * 32 + l31] = v1[r];
        }
      }
      __syncthreads();
      float s = 0.f;
      const float* tb = &T[erow * 260 + ecc * 16];
#pragma unroll
      for (int j = 0; j < 4; ++j) {
        const f32x4 x = *reinterpret_cast<const f32x4*>(tb + j * 4);
        s += __expf(x[0]) + __expf(x[1]) + __expf(x[2]) + __expf(x[3]);
      }
      s += __shfl_xor(s, 1); s += __shfl_xor(s, 2);
      s += __shfl_xor(s, 4); s += __shfl_xor(s, 8);
      if (ecc == 0) sLseF[m * 128 + h * 64 + erow] = __logf(s);
      __syncthreads();
    }
  };
  lsePass(acc[0][0], acc[0][1], 0);
  lsePass(acc[1][0], acc[1][1], 1);
  lsePass(ca[0], ca[1], 2);

  // fused symmetric-KL: sum of e^a(2a-b-c) + e^b(2b-a-c) + e^c(2c-a-b)
  float ks = 0.f;
#pragma unroll
  for (int rt = 0; rt < 2; ++rt)
#pragma unroll
    for (int r = 0; r < 16; ++r) {
      const int row = rp * 64 + rt * 32 + (r & 3) + 8 * (r >> 2) + 4 * hi;
      const float a = acc[0][rt][r] - sLseF[row];
      const float b = acc[1][rt][r] - sLseF[128 + row];
      const float c = ca[rt][r] - sLseF[256 + row];
      ks += __expf(a) * (2.f * a - b - c) + __expf(b) * (2.f * b - a - c) +
            __expf(c) * (2.f * c - a - b);
    }
#pragma unroll
  for (int off = 1; off < 64; off <<= 1)
    ks += __shfl_xor(ks, off);
  if (lane == 0) bredF[w] = ks;
  __syncthreads();
  if (tid == 0) {
    float s = 0.f;
#pragma unroll
    for (int i = 0; i < 16; ++i) s += bredF[i];
    atomicAdd(out, s * (1.f / 50331648.f));  // 1/(6 * 2N * C)
  }
}

extern "C" void kernel_launch(void* const* d_in, const int* in_sizes, int n_in,
                              void* d_out, int out_size, void* d_ws, size_t ws_size,
                              hipStream_t stream) {
  const float* src = (const float*)d_in[0];
  const float* trg = (const float*)d_in[1];
  const int* lab_s = (const int*)d_in[2];
  const int* lab_t = (const int*)d_in[3];
  float* out = (float*)d_out;

  char* p = (char*)d_ws;
  float* cnt_s = (float*)p;                  p += 1024;
  float* cnt_t = (float*)p;                  p += 1024;
  int* cur = (int*)p;                        p += 2048;
  int* idx = (int*)p;                        p += 512 * CAP * 4;
  unsigned short* Upk = (unsigned short*)p;  p += 2 * 131072 * 2;

  hipMemsetAsync(cur, 0, 2048, stream);
  k_bucket<<<128, 256, 0, stream>>>(lab_s, lab_t, cur, idx, out);
  k_gather<<<512, 256, 0, stream>>>(src, trg, cur, idx, Upk, cnt_s, cnt_t);
  k_main<<<256, 1024, 0, stream>>>(src, trg, Upk, cnt_s, cnt_t, out);
}